// Round 1
// baseline (989.803 us; speedup 1.0000x reference)
//
#include <hip/hip_runtime.h>
#include <math.h>

// Problem constants
constexpr int B    = 8;
constexpr int C    = 256;
constexpr int L    = 4096;   // 64*64
constexpr int CH   = 128;    // channels per branch
constexpr int NPOS = 256;    // positions per window (64*4 or 4*64)
// qw/kw/vw layout: [branch(2)][bw(128)][head(4)][d(32)][pos(256)]
constexpr size_t QKV_WIN_ELEMS = 2ull * 128 * 4 * 32 * 256;  // 8,388,608

// ---------------- K1: LayerNorm stats ----------------
__global__ __launch_bounds__(256) void k_ln_stats(const float* __restrict__ x,
                                                  float* __restrict__ mu,
                                                  float* __restrict__ rstd) {
    int b = blockIdx.x >> 4;                       // 16 blocks per batch
    int l = ((blockIdx.x & 15) << 8) + threadIdx.x;
    const float* xb = x + (size_t)b * C * L + l;
    float s = 0.f, s2 = 0.f;
    for (int ch = 0; ch < C; ++ch) {
        float v = xb[(size_t)ch * L];
        s += v; s2 += v * v;
    }
    float m   = s * (1.f / C);
    float var = s2 * (1.f / C) - m * m;
    mu[b * L + l]   = m;
    rstd[b * L + l] = rsqrtf(var + 1e-4f);
}

// ---------------- K2: LayerNorm apply (xn in [B,C,L]) ----------------
__global__ __launch_bounds__(256) void k_ln_apply(const float* __restrict__ x,
                                                  const float* __restrict__ mu,
                                                  const float* __restrict__ rstd,
                                                  const float* __restrict__ g,
                                                  const float* __restrict__ beta,
                                                  float* __restrict__ xn) {
    int idx = blockIdx.x * 256 + threadIdx.x;      // over B*C*L/4
    int l4 = idx & (L / 4 - 1);
    int bc = idx >> 10;
    int ch = bc & (C - 1);
    int b  = bc >> 8;
    float4 xv = ((const float4*)x)[idx];
    float4 m4 = ((const float4*)(mu + (size_t)b * L))[l4];
    float4 r4 = ((const float4*)(rstd + (size_t)b * L))[l4];
    float gg = g[ch], bb = beta[ch];
    float4 o;
    o.x = (xv.x - m4.x) * r4.x * gg + bb;
    o.y = (xv.y - m4.y) * r4.y * gg + bb;
    o.z = (xv.z - m4.z) * r4.z * gg + bb;
    o.w = (xv.w - m4.w) * r4.w * gg + bb;
    ((float4*)xn)[idx] = o;
}

// ---------------- K3: qkv GEMM + window-layout scatter ----------------
// qkv[j,l] = sum_ch wqkv[j,ch] * xn[b][ch,l];  j in [0,768)
__global__ __launch_bounds__(256) void k_qkv(const float* __restrict__ wqkv,
                                             const float* __restrict__ xn,
                                             float* __restrict__ qw,
                                             float* __restrict__ kw,
                                             float* __restrict__ vw) {
    __shared__ float sA[16][68];
    __shared__ float sB[16][68];
    int jt = blockIdx.x, lt = blockIdx.y, b = blockIdx.z;
    int j0 = jt * 64, l0 = lt * 64;
    int tid = threadIdx.x;
    float acc[4][4] = {};
    const float* Bbase = xn + (size_t)b * C * L;
    int ar = tid >> 2, ac4 = (tid & 3) << 2;       // A-tile: row, col*4
    int tl = tid & 63;
    for (int k0 = 0; k0 < C; k0 += 16) {
        float4 av = *(const float4*)(wqkv + (size_t)(j0 + ar) * C + k0 + ac4);
        sA[ac4 + 0][ar] = av.x; sA[ac4 + 1][ar] = av.y;
        sA[ac4 + 2][ar] = av.z; sA[ac4 + 3][ar] = av.w;
#pragma unroll
        for (int i = 0; i < 4; i++) {
            int kr = (tid >> 6) + i * 4;
            sB[kr][tl] = Bbase[(size_t)(k0 + kr) * L + l0 + tl];
        }
        __syncthreads();
#pragma unroll
        for (int kk = 0; kk < 16; ++kk) {
            float4 a4 = *(const float4*)&sA[kk][(tid >> 4) << 2];
            float4 b4 = *(const float4*)&sB[kk][(tid & 15) << 2];
            acc[0][0] += a4.x * b4.x; acc[0][1] += a4.x * b4.y; acc[0][2] += a4.x * b4.z; acc[0][3] += a4.x * b4.w;
            acc[1][0] += a4.y * b4.x; acc[1][1] += a4.y * b4.y; acc[1][2] += a4.y * b4.z; acc[1][3] += a4.y * b4.w;
            acc[2][0] += a4.z * b4.x; acc[2][1] += a4.z * b4.y; acc[2][2] += a4.z * b4.z; acc[2][3] += a4.z * b4.w;
            acc[3][0] += a4.w * b4.x; acc[3][1] += a4.w * b4.y; acc[3][2] += a4.w * b4.z; acc[3][3] += a4.w * b4.w;
        }
        __syncthreads();
    }
    // scatter to window layout
#pragma unroll
    for (int i = 0; i < 4; i++) {
        int jj = j0 + ((tid >> 4) << 2) + i;
        int sel = jj >> 8;            // 0=q 1=k 2=v
        int jr = jj & 255;
        int branch = jr >> 7;
        int chb = jr & 127;
        int d = chb >> 2, head = chb & 3;
        float* dst = (sel == 0) ? qw : ((sel == 1) ? kw : vw);
#pragma unroll
        for (int j = 0; j < 4; j++) {
            int ll = l0 + ((tid & 15) << 2) + j;
            int row = ll >> 6, col = ll & 63;
            int win, pos;
            if (branch == 0) { win = col >> 2; pos = (row << 2) | (col & 3); }
            else             { win = row >> 2; pos = ((row & 3) << 6) | col; }
            int bw = b * 16 + win;
            size_t idx = ((((size_t)branch * 128 + bw) * 4 + head) * 32 + d) * 256 + pos;
            dst[idx] = acc[i][j];
        }
    }
}

// ---------------- K5: attention + LePE ----------------
__global__ __launch_bounds__(256) void k_attn(const float* __restrict__ qw,
                                              const float* __restrict__ kw,
                                              const float* __restrict__ vw,
                                              const float* __restrict__ lw1,
                                              const float* __restrict__ lb1,
                                              const float* __restrict__ lw2,
                                              const float* __restrict__ lb2,
                                              float* __restrict__ attn_out,
                                              float* __restrict__ xcat) {
    __shared__ float kt[32 * 256];
    __shared__ float vt[32 * 256];
    int bid = blockIdx.x;
    int branch = bid >> 9;
    int bw = (bid >> 2) & 127;
    int head = bid & 3;
    int tid = threadIdx.x;

    size_t whbase = ((((size_t)branch * 128 + bw) * 4 + head) * 32) * 256;
    const float* kg = kw + whbase;
    const float* vg = vw + whbase;
    const float* qg = qw + whbase;
#pragma unroll
    for (int i = 0; i < 8; i++) {
        ((float4*)kt)[tid + 256 * i] = ((const float4*)kg)[tid + 256 * i];
        ((float4*)vt)[tid + 256 * i] = ((const float4*)vg)[tid + 256 * i];
    }
    float q[32];
#pragma unroll
    for (int d = 0; d < 32; ++d) q[d] = qg[d * 256 + tid] * 0.125f;  // fold scale
    __syncthreads();

    // pass 1: online max + sum
    float m = -1e30f, lsum = 0.f;
    for (int c0 = 0; c0 < 256; c0 += 4) {
        float4 s = {0.f, 0.f, 0.f, 0.f};
#pragma unroll
        for (int d = 0; d < 32; ++d) {
            float4 kk = *(const float4*)&kt[d * 256 + c0];
            s.x += q[d] * kk.x; s.y += q[d] * kk.y;
            s.z += q[d] * kk.z; s.w += q[d] * kk.w;
        }
        float cm = fmaxf(fmaxf(s.x, s.y), fmaxf(s.z, s.w));
        float nm = fmaxf(m, cm);
        lsum = lsum * __expf(m - nm) + __expf(s.x - nm) + __expf(s.y - nm)
             + __expf(s.z - nm) + __expf(s.w - nm);
        m = nm;
    }
    float inv = 1.f / lsum;

    // pass 2: recompute, write attn, accumulate PV
    float o[32];
#pragma unroll
    for (int d = 0; d < 32; ++d) o[d] = 0.f;
    float* arow = attn_out + (size_t)branch * 33554432ull
                + (((size_t)(bw * 4 + head)) * 256 + tid) * 256;
    for (int c0 = 0; c0 < 256; c0 += 4) {
        float4 s = {0.f, 0.f, 0.f, 0.f};
#pragma unroll
        for (int d = 0; d < 32; ++d) {
            float4 kk = *(const float4*)&kt[d * 256 + c0];
            s.x += q[d] * kk.x; s.y += q[d] * kk.y;
            s.z += q[d] * kk.z; s.w += q[d] * kk.w;
        }
        float4 a;
        a.x = __expf(s.x - m) * inv; a.y = __expf(s.y - m) * inv;
        a.z = __expf(s.z - m) * inv; a.w = __expf(s.w - m) * inv;
        *(float4*)(arow + c0) = a;
#pragma unroll
        for (int d = 0; d < 32; ++d) {
            float4 vv = *(const float4*)&vt[d * 256 + c0];
            o[d] += a.x * vv.x + a.y * vv.y + a.z * vv.z + a.w * vv.w;
        }
    }

    // LePE: depthwise 3x3 over window image + bias
    const float* lw = branch ? lw2 : lw1;
    const float* lb = branch ? lb2 : lb1;
    int p = tid;
    int hs, ws;
    if (branch == 0) { hs = p >> 2; ws = p & 3; }
    else             { hs = p >> 6; ws = p & 63; }
#pragma unroll
    for (int d = 0; d < 32; ++d) {
        float acc = lb[d * 4 + head];
#pragma unroll
        for (int ky = 0; ky < 3; ky++) {
#pragma unroll
            for (int kx = 0; kx < 3; kx++) {
                int ny = hs + ky - 1, nx = ws + kx - 1;
                bool ok; int np;
                if (branch == 0) { ok = (ny >= 0 && ny < 64 && nx >= 0 && nx < 4);  np = (ny << 2) | (nx & 3); }
                else             { ok = (ny >= 0 && ny < 4  && nx >= 0 && nx < 64); np = (ny << 6) | (nx & 63); }
                if (ok) acc += lw[(d * 4 + head) * 9 + ky * 3 + kx] * vt[d * 256 + np];
            }
        }
        o[d] += acc;
    }

    // write o to xcat [B][256][L]
    int win = bw & 15, b = bw >> 4;
    int row, col;
    if (branch == 0) { row = p >> 2; col = (win << 2) | (p & 3); }
    else             { row = (win << 2) | (p >> 6); col = p & 63; }
    size_t lpix = (size_t)row * 64 + col;
#pragma unroll
    for (int d = 0; d < 32; ++d) {
        int chg = branch * 128 + d * 4 + head;
        xcat[((size_t)b * 256 + chg) * 4096 + lpix] = o[d];
    }
}

// ---------------- K6: projection GEMM ----------------
__global__ __launch_bounds__(256) void k_proj(const float* __restrict__ pw,
                                              const float* __restrict__ pb,
                                              const float* __restrict__ xcat,
                                              float* __restrict__ out) {
    __shared__ float sA[16][68];
    __shared__ float sB[16][68];
    int jt = blockIdx.x, lt = blockIdx.y, b = blockIdx.z;
    int j0 = jt * 64, l0 = lt * 64;
    int tid = threadIdx.x;
    float acc[4][4] = {};
    int ar = tid >> 2, ac4 = (tid & 3) << 2;
    int tl = tid & 63;
    for (int k0 = 0; k0 < 256; k0 += 16) {
        float4 av = *(const float4*)(pw + (size_t)(j0 + ar) * 256 + k0 + ac4);
        sA[ac4 + 0][ar] = av.x; sA[ac4 + 1][ar] = av.y;
        sA[ac4 + 2][ar] = av.z; sA[ac4 + 3][ar] = av.w;
#pragma unroll
        for (int i = 0; i < 4; i++) {
            int kr = (tid >> 6) + i * 4;
            sB[kr][tl] = xcat[((size_t)b * 256 + k0 + kr) * 4096 + l0 + tl];
        }
        __syncthreads();
#pragma unroll
        for (int kk = 0; kk < 16; ++kk) {
            float4 a4 = *(const float4*)&sA[kk][(tid >> 4) << 2];
            float4 b4 = *(const float4*)&sB[kk][(tid & 15) << 2];
            acc[0][0] += a4.x * b4.x; acc[0][1] += a4.x * b4.y; acc[0][2] += a4.x * b4.z; acc[0][3] += a4.x * b4.w;
            acc[1][0] += a4.y * b4.x; acc[1][1] += a4.y * b4.y; acc[1][2] += a4.y * b4.z; acc[1][3] += a4.y * b4.w;
            acc[2][0] += a4.z * b4.x; acc[2][1] += a4.z * b4.y; acc[2][2] += a4.z * b4.z; acc[2][3] += a4.z * b4.w;
            acc[3][0] += a4.w * b4.x; acc[3][1] += a4.w * b4.y; acc[3][2] += a4.w * b4.z; acc[3][3] += a4.w * b4.w;
        }
        __syncthreads();
    }
#pragma unroll
    for (int i = 0; i < 4; i++) {
        int jj = j0 + ((tid >> 4) << 2) + i;
        float bias = pb[jj];
        float4 r4;
        r4.x = acc[i][0] + bias; r4.y = acc[i][1] + bias;
        r4.z = acc[i][2] + bias; r4.w = acc[i][3] + bias;
        *(float4*)(out + ((size_t)b * 256 + jj) * 4096 + l0 + ((tid & 15) << 2)) = r4;
    }
}

extern "C" void kernel_launch(void* const* d_in, const int* in_sizes, int n_in,
                              void* d_out, int out_size, void* d_ws, size_t ws_size,
                              hipStream_t stream) {
    const float* x    = (const float*)d_in[0];
    const float* ln_g = (const float*)d_in[1];
    const float* ln_b = (const float*)d_in[2];
    const float* wqkv = (const float*)d_in[3];
    const float* pw   = (const float*)d_in[4];
    const float* pb   = (const float*)d_in[5];
    const float* lw1  = (const float*)d_in[6];
    const float* lb1  = (const float*)d_in[7];
    const float* lw2  = (const float*)d_in[8];
    const float* lb2  = (const float*)d_in[9];

    float* ws   = (float*)d_ws;
    float* mu   = ws;                        // 32768
    float* rstd = ws + 32768;                // 32768
    float* xn   = ws + 65536;                // 8,388,608  (aliased as xcat later)
    float* qw   = xn + 8388608;              // 8,388,608
    float* kw   = qw + 8388608;
    float* vw   = kw + 8388608;
    float* xcat = xn;                        // xn dead after k_qkv
    float* out  = (float*)d_out;
    float* attn = out + 8388608;             // attn1 then attn2

    k_ln_stats<<<128, 256, 0, stream>>>(x, mu, rstd);
    k_ln_apply<<<8192, 256, 0, stream>>>(x, mu, rstd, ln_g, ln_b, xn);
    k_qkv<<<dim3(12, 64, 8), 256, 0, stream>>>(wqkv, xn, qw, kw, vw);
    k_attn<<<1024, 256, 0, stream>>>(qw, kw, vw, lw1, lb1, lw2, lb2, attn, xcat);
    k_proj<<<dim3(4, 64, 8), 256, 0, stream>>>(pw, pb, xcat, out);
}

// Round 2
// 677.029 us; speedup vs baseline: 1.4620x; 1.4620x over previous
//
#include <hip/hip_runtime.h>
#include <math.h>

typedef short bf8 __attribute__((ext_vector_type(8)));
typedef float f4  __attribute__((ext_vector_type(4)));

__device__ inline float b2f(unsigned short u) {
    return __uint_as_float(((unsigned int)u) << 16);
}
__device__ inline unsigned short f2b(float f) {
    unsigned int u = __float_as_uint(f);
    u = (u + 0x7fffu + ((u >> 16) & 1u)) >> 16;
    return (unsigned short)u;
}

// ---------------- K1: LayerNorm stats ----------------
__global__ __launch_bounds__(256) void k_ln_stats(const float* __restrict__ x,
                                                  float* __restrict__ mu,
                                                  float* __restrict__ rstd) {
    int b = blockIdx.x >> 4;
    int l = ((blockIdx.x & 15) << 8) + threadIdx.x;
    const float* xb = x + (size_t)b * 256 * 4096 + l;
    float s = 0.f, s2 = 0.f;
    for (int ch = 0; ch < 256; ++ch) {
        float v = xb[(size_t)ch * 4096];
        s += v; s2 += v * v;
    }
    float m   = s * (1.f / 256.f);
    float var = s2 * (1.f / 256.f) - m * m;
    mu[b * 4096 + l]   = m;
    rstd[b * 4096 + l] = rsqrtf(var + 1e-4f);
}

// ---------------- K2: LayerNorm apply (xn in [B,C,L]) ----------------
__global__ __launch_bounds__(256) void k_ln_apply(const float* __restrict__ x,
                                                  const float* __restrict__ mu,
                                                  const float* __restrict__ rstd,
                                                  const float* __restrict__ g,
                                                  const float* __restrict__ beta,
                                                  float* __restrict__ xn) {
    int idx = blockIdx.x * 256 + threadIdx.x;
    int l4 = idx & (1024 - 1);
    int bc = idx >> 10;
    int ch = bc & 255;
    int b  = bc >> 8;
    float4 xv = ((const float4*)x)[idx];
    float4 m4 = ((const float4*)(mu + (size_t)b * 4096))[l4];
    float4 r4 = ((const float4*)(rstd + (size_t)b * 4096))[l4];
    float gg = g[ch], bb = beta[ch];
    float4 o;
    o.x = (xv.x - m4.x) * r4.x * gg + bb;
    o.y = (xv.y - m4.y) * r4.y * gg + bb;
    o.z = (xv.z - m4.z) * r4.z * gg + bb;
    o.w = (xv.w - m4.w) * r4.w * gg + bb;
    ((float4*)xn)[idx] = o;
}

// ---------------- K3: qkv GEMM + window-layout scatter (bf16 out) ----------------
// q,k -> [branch][bw][head][pos][d] bf16 (q pre-scaled by 0.125)
// v   -> [branch][bw][head][d][pos] bf16
__global__ __launch_bounds__(256) void k_qkv(const float* __restrict__ wqkv,
                                             const float* __restrict__ xn,
                                             unsigned short* __restrict__ qw,
                                             unsigned short* __restrict__ kw,
                                             unsigned short* __restrict__ vw) {
    __shared__ float sA[16][68];
    __shared__ float sB[16][68];
    int jt = blockIdx.x, lt = blockIdx.y, b = blockIdx.z;
    int j0 = jt * 64, l0 = lt * 64;
    int tid = threadIdx.x;
    float acc[4][4] = {};
    const float* Bbase = xn + (size_t)b * 256 * 4096;
    int ar = tid >> 2, ac4 = (tid & 3) << 2;
    int tl = tid & 63;
    for (int k0 = 0; k0 < 256; k0 += 16) {
        float4 av = *(const float4*)(wqkv + (size_t)(j0 + ar) * 256 + k0 + ac4);
        sA[ac4 + 0][ar] = av.x; sA[ac4 + 1][ar] = av.y;
        sA[ac4 + 2][ar] = av.z; sA[ac4 + 3][ar] = av.w;
#pragma unroll
        for (int i = 0; i < 4; i++) {
            int kr = (tid >> 6) + i * 4;
            sB[kr][tl] = Bbase[(size_t)(k0 + kr) * 4096 + l0 + tl];
        }
        __syncthreads();
#pragma unroll
        for (int kk = 0; kk < 16; ++kk) {
            float4 a4 = *(const float4*)&sA[kk][(tid >> 4) << 2];
            float4 b4 = *(const float4*)&sB[kk][(tid & 15) << 2];
            acc[0][0] += a4.x * b4.x; acc[0][1] += a4.x * b4.y; acc[0][2] += a4.x * b4.z; acc[0][3] += a4.x * b4.w;
            acc[1][0] += a4.y * b4.x; acc[1][1] += a4.y * b4.y; acc[1][2] += a4.y * b4.z; acc[1][3] += a4.y * b4.w;
            acc[2][0] += a4.z * b4.x; acc[2][1] += a4.z * b4.y; acc[2][2] += a4.z * b4.z; acc[2][3] += a4.z * b4.w;
            acc[3][0] += a4.w * b4.x; acc[3][1] += a4.w * b4.y; acc[3][2] += a4.w * b4.z; acc[3][3] += a4.w * b4.w;
        }
        __syncthreads();
    }
#pragma unroll
    for (int i = 0; i < 4; i++) {
        int jj = j0 + ((tid >> 4) << 2) + i;
        int sel = jj >> 8;            // 0=q 1=k 2=v
        int jr = jj & 255;
        int branch = jr >> 7;
        int chb = jr & 127;
        int d = chb >> 2, head = chb & 3;
        unsigned short* dst = (sel == 0) ? qw : ((sel == 1) ? kw : vw);
#pragma unroll
        for (int j = 0; j < 4; j++) {
            int ll = l0 + ((tid & 15) << 2) + j;
            int row = ll >> 6, col = ll & 63;
            int win, pos;
            if (branch == 0) { win = col >> 2; pos = (row << 2) | (col & 3); }
            else             { win = row >> 2; pos = ((row & 3) << 6) | col; }
            int bw = b * 16 + win;
            float val = acc[i][j];
            if (sel == 0) val *= 0.125f;
            size_t idx;
            if (sel == 2)
                idx = ((((size_t)branch * 128 + bw) * 4 + head) * 32 + d) * 256 + pos;
            else
                idx = ((((size_t)branch * 128 + bw) * 4 + head) * 256 + pos) * 32 + d;
            dst[idx] = f2b(val);
        }
    }
}

// ---------------- K4: MFMA attention + LePE ----------------
// 1 block = (branch, bw, head); 4 waves; wave w owns query rows 64w..64w+63
__global__ __launch_bounds__(256, 3) void k_attn(const unsigned short* __restrict__ qw,
                                                 const unsigned short* __restrict__ kw,
                                                 const unsigned short* __restrict__ vw,
                                                 const float* __restrict__ lw1,
                                                 const float* __restrict__ lb1,
                                                 const float* __restrict__ lw2,
                                                 const float* __restrict__ lb2,
                                                 float* __restrict__ attn_out,
                                                 float* __restrict__ xcat) {
    __shared__ __align__(16) char smem[49792];
    float*          olds = (float*)smem;            // 32*257 floats = 32896 B (O transpose; first 4KB = P staging)
    unsigned short* vt   = (unsigned short*)(smem + 32896);  // 32 rows * pitch 264 bf16 = 16896 B

    int bid = blockIdx.x;
    int branch = bid >> 9;
    int bw = (bid >> 2) & 127;
    int head = bid & 3;
    int tid = threadIdx.x;
    int w = tid >> 6, lane = tid & 63;
    int ln15 = lane & 15, quad = lane >> 4;
    int rowbase = w * 64;

    size_t base = (((size_t)branch * 128 + bw) * 4 + head) * 8192;
    const unsigned short* qb = qw + base;   // [pos][d]
    const unsigned short* kb = kw + base;   // [pos][d]
    const unsigned short* vb = vw + base;   // [d][pos]

    // stage V into LDS (pitch 264)
    {
        int d = tid >> 3, ck = (tid & 7) * 32;
        const uint4* s = (const uint4*)(vb + d * 256 + ck);
        uint4* dst = (uint4*)(vt + d * 264 + ck);
        dst[0] = s[0]; dst[1] = s[1]; dst[2] = s[2]; dst[3] = s[3];
    }

    // Q fragments (A-layout): lane holds Q[row=ln15][k=quad*8..+8]
    bf8 qf[4];
#pragma unroll
    for (int rt = 0; rt < 4; rt++)
        qf[rt] = *(const bf8*)(qb + (rowbase + rt * 16 + ln15) * 32 + quad * 8);

    const f4 z = {0.f, 0.f, 0.f, 0.f};

    // ---- pass 1: row sums of exp(s) ----
    f4 lsum[4] = {z, z, z, z};
    for (int jtile = 0; jtile < 16; jtile++) {
        bf8 kf = *(const bf8*)(kb + (jtile * 16 + ln15) * 32 + quad * 8);
#pragma unroll
        for (int rt = 0; rt < 4; rt++) {
            f4 s = __builtin_amdgcn_mfma_f32_16x16x32_bf16(qf[rt], kf, z, 0, 0, 0);
            lsum[rt].x += __expf(s.x);
            lsum[rt].y += __expf(s.y);
            lsum[rt].z += __expf(s.z);
            lsum[rt].w += __expf(s.w);
        }
    }
    f4 inv[4];
#pragma unroll
    for (int rt = 0; rt < 4; rt++) {
        float a0 = lsum[rt].x, a1 = lsum[rt].y, a2 = lsum[rt].z, a3 = lsum[rt].w;
#pragma unroll
        for (int m = 1; m < 16; m <<= 1) {
            a0 += __shfl_xor(a0, m); a1 += __shfl_xor(a1, m);
            a2 += __shfl_xor(a2, m); a3 += __shfl_xor(a3, m);
        }
        inv[rt].x = 1.f / a0; inv[rt].y = 1.f / a1;
        inv[rt].z = 1.f / a2; inv[rt].w = 1.f / a3;
    }

    __syncthreads();   // V staged before any vt read

    // ---- pass 2: recompute S, write attn, PV via MFMA ----
    unsigned short* plw = ((unsigned short*)olds) + w * 512;  // 16x32 bf16 P staging per wave
    float* abase = attn_out + (size_t)branch * 33554432ull
                 + ((size_t)(bw * 4 + head)) * 65536;
    f4 oacc[4][2] = {{z, z}, {z, z}, {z, z}, {z, z}};
    for (int t = 0; t < 8; t++) {
        int c0 = t * 32;
        bf8 kf0 = *(const bf8*)(kb + (c0 + ln15) * 32 + quad * 8);
        bf8 kf1 = *(const bf8*)(kb + (c0 + 16 + ln15) * 32 + quad * 8);
        bf8 vf0 = *(const bf8*)(vt + ln15 * 264 + c0 + quad * 8);
        bf8 vf1 = *(const bf8*)(vt + (16 + ln15) * 264 + c0 + quad * 8);
#pragma unroll
        for (int rt = 0; rt < 4; rt++) {
            f4 s0 = __builtin_amdgcn_mfma_f32_16x16x32_bf16(qf[rt], kf0, z, 0, 0, 0);
            f4 s1 = __builtin_amdgcn_mfma_f32_16x16x32_bf16(qf[rt], kf1, z, 0, 0, 0);
            f4 p0, p1;
            p0.x = __expf(s0.x) * inv[rt].x; p0.y = __expf(s0.y) * inv[rt].y;
            p0.z = __expf(s0.z) * inv[rt].z; p0.w = __expf(s0.w) * inv[rt].w;
            p1.x = __expf(s1.x) * inv[rt].x; p1.y = __expf(s1.y) * inv[rt].y;
            p1.z = __expf(s1.z) * inv[rt].z; p1.w = __expf(s1.w) * inv[rt].w;
            float* ar = abase + (size_t)(rowbase + rt * 16 + quad * 4) * 256 + c0 + ln15;
            ar[0]   = p0.x; ar[256] = p0.y; ar[512] = p0.z; ar[768] = p0.w;
            ar[16]  = p1.x; ar[272] = p1.y; ar[528] = p1.z; ar[784] = p1.w;
            // stage P (bf16, A-layout source tile 16 rows x 32 cols, pitch 32)
            plw[(quad * 4 + 0) * 32 + ln15]      = f2b(p0.x);
            plw[(quad * 4 + 1) * 32 + ln15]      = f2b(p0.y);
            plw[(quad * 4 + 2) * 32 + ln15]      = f2b(p0.z);
            plw[(quad * 4 + 3) * 32 + ln15]      = f2b(p0.w);
            plw[(quad * 4 + 0) * 32 + 16 + ln15] = f2b(p1.x);
            plw[(quad * 4 + 1) * 32 + 16 + ln15] = f2b(p1.y);
            plw[(quad * 4 + 2) * 32 + 16 + ln15] = f2b(p1.z);
            plw[(quad * 4 + 3) * 32 + 16 + ln15] = f2b(p1.w);
            bf8 pf = *(const bf8*)(plw + ln15 * 32 + quad * 8);
            oacc[rt][0] = __builtin_amdgcn_mfma_f32_16x16x32_bf16(pf, vf0, oacc[rt][0], 0, 0, 0);
            oacc[rt][1] = __builtin_amdgcn_mfma_f32_16x16x32_bf16(pf, vf1, oacc[rt][1], 0, 0, 0);
        }
    }

    __syncthreads();   // all P staging reads done before O overwrites olds
    // O (C-layout) -> olds[d * 257 + pos]
#pragma unroll
    for (int rt = 0; rt < 4; rt++)
#pragma unroll
        for (int dt = 0; dt < 2; dt++) {
            int d = dt * 16 + ln15;
            int r = rowbase + rt * 16 + quad * 4;
            olds[d * 257 + r + 0] = oacc[rt][dt][0];
            olds[d * 257 + r + 1] = oacc[rt][dt][1];
            olds[d * 257 + r + 2] = oacc[rt][dt][2];
            olds[d * 257 + r + 3] = oacc[rt][dt][3];
        }
    __syncthreads();

    // ---- LePE + xcat write: thread = position ----
    const float* lw = branch ? lw2 : lw1;
    const float* lb = branch ? lb2 : lb1;
    int p = tid;
    int hs, ws_;
    if (branch == 0) { hs = p >> 2; ws_ = p & 3; }
    else             { hs = p >> 6; ws_ = p & 63; }
    int win = bw & 15, b = bw >> 4;
    int row, col;
    if (branch == 0) { row = p >> 2; col = (win << 2) | (p & 3); }
    else             { row = (win << 2) | (p >> 6); col = p & 63; }
    size_t lpix = (size_t)row * 64 + col;
#pragma unroll
    for (int d = 0; d < 32; ++d) {
        float acc = lb[d * 4 + head];
#pragma unroll
        for (int ky = 0; ky < 3; ky++) {
#pragma unroll
            for (int kx = 0; kx < 3; kx++) {
                int ny = hs + ky - 1, nx = ws_ + kx - 1;
                bool ok; int np;
                if (branch == 0) { ok = (ny >= 0 && ny < 64 && nx >= 0 && nx < 4);  np = (ny << 2) | (nx & 3); }
                else             { ok = (ny >= 0 && ny < 4  && nx >= 0 && nx < 64); np = (ny << 6) | (nx & 63); }
                if (ok) acc += lw[(d * 4 + head) * 9 + ky * 3 + kx] * b2f(vt[d * 264 + np]);
            }
        }
        float oval = olds[d * 257 + p] + acc;
        int chg = branch * 128 + d * 4 + head;
        xcat[((size_t)b * 256 + chg) * 4096 + lpix] = oval;
    }
}

// ---------------- K5: projection GEMM ----------------
__global__ __launch_bounds__(256) void k_proj(const float* __restrict__ pw,
                                              const float* __restrict__ pb,
                                              const float* __restrict__ xcat,
                                              float* __restrict__ out) {
    __shared__ float sA[16][68];
    __shared__ float sB[16][68];
    int jt = blockIdx.x, lt = blockIdx.y, b = blockIdx.z;
    int j0 = jt * 64, l0 = lt * 64;
    int tid = threadIdx.x;
    float acc[4][4] = {};
    int ar = tid >> 2, ac4 = (tid & 3) << 2;
    int tl = tid & 63;
    for (int k0 = 0; k0 < 256; k0 += 16) {
        float4 av = *(const float4*)(pw + (size_t)(j0 + ar) * 256 + k0 + ac4);
        sA[ac4 + 0][ar] = av.x; sA[ac4 + 1][ar] = av.y;
        sA[ac4 + 2][ar] = av.z; sA[ac4 + 3][ar] = av.w;
#pragma unroll
        for (int i = 0; i < 4; i++) {
            int kr = (tid >> 6) + i * 4;
            sB[kr][tl] = xcat[((size_t)b * 256 + k0 + kr) * 4096 + l0 + tl];
        }
        __syncthreads();
#pragma unroll
        for (int kk = 0; kk < 16; ++kk) {
            float4 a4 = *(const float4*)&sA[kk][(tid >> 4) << 2];
            float4 b4 = *(const float4*)&sB[kk][(tid & 15) << 2];
            acc[0][0] += a4.x * b4.x; acc[0][1] += a4.x * b4.y; acc[0][2] += a4.x * b4.z; acc[0][3] += a4.x * b4.w;
            acc[1][0] += a4.y * b4.x; acc[1][1] += a4.y * b4.y; acc[1][2] += a4.y * b4.z; acc[1][3] += a4.y * b4.w;
            acc[2][0] += a4.z * b4.x; acc[2][1] += a4.z * b4.y; acc[2][2] += a4.z * b4.z; acc[2][3] += a4.z * b4.w;
            acc[3][0] += a4.w * b4.x; acc[3][1] += a4.w * b4.y; acc[3][2] += a4.w * b4.z; acc[3][3] += a4.w * b4.w;
        }
        __syncthreads();
    }
#pragma unroll
    for (int i = 0; i < 4; i++) {
        int jj = j0 + ((tid >> 4) << 2) + i;
        float bias = pb[jj];
        float4 r4;
        r4.x = acc[i][0] + bias; r4.y = acc[i][1] + bias;
        r4.z = acc[i][2] + bias; r4.w = acc[i][3] + bias;
        *(float4*)(out + ((size_t)b * 256 + jj) * 4096 + l0 + ((tid & 15) << 2)) = r4;
    }
}

extern "C" void kernel_launch(void* const* d_in, const int* in_sizes, int n_in,
                              void* d_out, int out_size, void* d_ws, size_t ws_size,
                              hipStream_t stream) {
    const float* x    = (const float*)d_in[0];
    const float* ln_g = (const float*)d_in[1];
    const float* ln_b = (const float*)d_in[2];
    const float* wqkv = (const float*)d_in[3];
    const float* pw   = (const float*)d_in[4];
    const float* pb   = (const float*)d_in[5];
    const float* lw1  = (const float*)d_in[6];
    const float* lb1  = (const float*)d_in[7];
    const float* lw2  = (const float*)d_in[8];
    const float* lb2  = (const float*)d_in[9];

    float* ws   = (float*)d_ws;
    float* mu   = ws;
    float* rstd = ws + 32768;
    float* xn   = ws + 65536;                           // 8,388,608 floats (aliased xcat)
    unsigned short* qw = (unsigned short*)(xn + 8388608);  // 8,388,608 bf16
    unsigned short* kw = qw + 8388608;
    unsigned short* vw = kw + 8388608;
    float* xcat = xn;
    float* out  = (float*)d_out;
    float* attn = out + 8388608;

    k_ln_stats<<<128, 256, 0, stream>>>(x, mu, rstd);
    k_ln_apply<<<8192, 256, 0, stream>>>(x, mu, rstd, ln_g, ln_b, xn);
    k_qkv<<<dim3(12, 64, 8), 256, 0, stream>>>(wqkv, xn, qw, kw, vw);
    k_attn<<<1024, 256, 0, stream>>>(qw, kw, vw, lw1, lb1, lw2, lb2, attn, xcat);
    k_proj<<<dim3(4, 64, 8), 256, 0, stream>>>(pw, pb, xcat, out);
}